// Round 4
// baseline (1275.794 us; speedup 1.0000x reference)
//
#include <hip/hip_runtime.h>
#include <hip/hip_bf16.h>

// Problem constants
#define B_SZ   4
#define S_LEN  2048
#define E_DIM  1024
#define H_NUM  16
#define D_DIM  64
#define M_ROWS (B_SZ * S_LEN)            // 8192
#define QK_SCALE 0.1803368801111204f     // (1/sqrt(64)) * log2(e): softmax in exp2 domain

typedef __attribute__((ext_vector_type(8))) __bf16 bf16x8;
typedef __attribute__((ext_vector_type(4))) float  f32x4;

__device__ __forceinline__ bf16x8 load8(const void* p) {
    return __builtin_bit_cast(bf16x8, *reinterpret_cast<const uint4*>(p));
}

#if defined(__has_builtin)
#if __has_builtin(__builtin_amdgcn_exp2f)
#define EXP2F(x) __builtin_amdgcn_exp2f(x)
#endif
#if __has_builtin(__builtin_amdgcn_global_load_lds)
#define HAVE_GLL 1
#endif
#endif
#ifndef EXP2F
#define EXP2F(x) exp2f(x)
#endif

// 16B-per-lane global->LDS stage (wave-uniform LDS base, lane i -> base+16i).
__device__ __forceinline__ void stage16(const __hip_bfloat16* g, __hip_bfloat16* lbase, int lane) {
#ifdef HAVE_GLL
    __builtin_amdgcn_global_load_lds((const __attribute__((address_space(1))) unsigned int*)g,
                                     (__attribute__((address_space(3))) unsigned int*)lbase,
                                     16, 0, 0);
#else
    reinterpret_cast<uint4*>(lbase)[lane] = *reinterpret_cast<const uint4*>(g);
#endif
}

// ---------------------------------------------------------------------------
// f32 -> bf16 convert, 8 elements/thread.
// ---------------------------------------------------------------------------
__global__ __launch_bounds__(256) void cvt_f32_bf16(const float* __restrict__ s,
                                                    __hip_bfloat16* __restrict__ d,
                                                    int n8)
{
    const int i = blockIdx.x * 256 + threadIdx.x;
    if (i >= n8) return;
    const float4 a = reinterpret_cast<const float4*>(s)[i * 2];
    const float4 b = reinterpret_cast<const float4*>(s)[i * 2 + 1];
    __hip_bfloat16 o[8];
    o[0] = __float2bfloat16(a.x); o[1] = __float2bfloat16(a.y);
    o[2] = __float2bfloat16(a.z); o[3] = __float2bfloat16(a.w);
    o[4] = __float2bfloat16(b.x); o[5] = __float2bfloat16(b.y);
    o[6] = __float2bfloat16(b.z); o[7] = __float2bfloat16(b.w);
    reinterpret_cast<uint4*>(d)[i] = *reinterpret_cast<uint4*>(o);
}

// ---------------------------------------------------------------------------
// Pipelined GEMM: C = A @ W^T + bias.  BM=128, BN=256, BK=32, K=1024.
// THIS ROUND: 256 threads = 4 waves, wave tile 128x64 (8x4 16x16 frags).
// MFMA/ds_read ratio 32/12 = 2.67 (was 16/8 = 2.0): per-CU LDS-read demand
// (96 b128 x 12cyc = 1152) now BELOW MFMA demand (1242 cyc) -> MFMA-bound.
// 3-buffer LDS ring (72KB) -> 2 blocks/CU; prefetch distance 2; 6 loads/stage
// -> vmcnt(6) steady (never 0 in loop), tail 6 -> 0.
// LDS swizzle (T2): 128B lines (row-pairs), granule g XOR (line&7); linear
// global_load_lds dest + inverse-permuted global SOURCE + same XOR on ds_read.
// Staging calls step lines by 32 (== 0 mod 8) so source ptrs differ by
// constant 64*E row offsets; swizzle formulas are call-invariant.
// Epilogue MODE: 0 bf16 [M][E]; 1 f32 [M][E]; 2 bf16 heads [bh][s][d];
//               3 bf16 heads-T [bh][d][s] (packed 8B stores along s).
// ---------------------------------------------------------------------------
struct GemmArgs {
    const __hip_bfloat16* A[3];
    const __hip_bfloat16* W[3];
    const float* bias[3];
    void* C[3];
    float scale[3];
    int mode[3];
};

__global__ __launch_bounds__(256, 2) void gemm_bt(GemmArgs g)
{
    __shared__ __attribute__((aligned(16))) char lds_raw[3 * 24576];   // 72 KB ring

    const int tid = threadIdx.x;
    const int wid = tid >> 6, lane = tid & 63;
    const int quad = lane >> 4, l16 = lane & 15;

    const int seg = blockIdx.x >> 8;
    int bid = blockIdx.x & 255;
    bid = (bid & 7) * 32 + (bid >> 3);          // XCD-aware swizzle (bijective, 256 wg)
    const int bm = bid >> 2, bn = bid & 3;      // 64 x 4 tiles of 128x256
    const int row0 = bm * 128, col0 = bn * 256;

    const __hip_bfloat16* A = g.A[seg];
    const __hip_bfloat16* W = g.W[seg];

    // --- staging source mapping (linear LDS dest, inverse-swizzled source) ---
    // granule gidx = call*256 + tid; line = gidx>>3, gr = gidx&7;
    // glin = gr ^ (line&7); row = 2*line + (glin>>2); ks = glin&3.
    // call steps line by +32 -> (line&7) invariant -> row steps by +64 only.
    const int s_line = tid >> 3, s_gr = tid & 7;
    const int glin  = s_gr ^ (s_line & 7);
    const int s_row = (s_line << 1) + (glin >> 2);
    const int s_ks  = glin & 3;
    const __hip_bfloat16* gA0 = A + (size_t)(row0 + s_row) * E_DIM + s_ks * 8;
    const __hip_bfloat16* gB0 = W + (size_t)(col0 + s_row) * E_DIM + s_ks * 8;
    const int stW = wid << 10;                  // wave-uniform LDS byte offset

    // --- swizzled ds_read byte offsets (per lane) ---
    const int rg   = (((l16 & 1) << 2) | quad) ^ ((l16 >> 1) & 7);
    const int rbase = (l16 >> 1) * 128 + rg * 16;

    f32x4 acc[8][4];
    const f32x4 zero = {0.f, 0.f, 0.f, 0.f};
#pragma unroll
    for (int i = 0; i < 8; i++)
#pragma unroll
        for (int j = 0; j < 4; j++) acc[i][j] = zero;

    auto stage_t = [&](int t) {
        char* b = lds_raw + (t % 3) * 24576;
        const int ko = t * 32;
        // A: 128 rows x 32k = 8KB, 2 calls
        stage16(gA0 + ko,                          (__hip_bfloat16*)(b + stW), lane);
        stage16(gA0 + (size_t)64 * E_DIM + ko,     (__hip_bfloat16*)(b + 4096 + stW), lane);
        // B: 256 rows x 32k = 16KB, 4 calls
        char* bB = b + 8192;
#pragma unroll
        for (int c = 0; c < 4; c++)
            stage16(gB0 + (size_t)(64 * c) * E_DIM + ko, (__hip_bfloat16*)(bB + c * 4096 + stW), lane);
    };

    auto body = [&](int t, bool stg) {
        __builtin_amdgcn_s_barrier();
        __builtin_amdgcn_sched_barrier(0);
        if (stg) stage_t(t + 2);
        const char* ab = lds_raw + (t % 3) * 24576;
        bf16x8 af[8], bf[4];
#pragma unroll
        for (int i = 0; i < 8; i++) af[i] = load8(ab + rbase + i * 1024);
#pragma unroll
        for (int j = 0; j < 4; j++) bf[j] = load8(ab + 8192 + wid * 4096 + rbase + j * 1024);
        __builtin_amdgcn_s_setprio(1);
#pragma unroll
        for (int i = 0; i < 8; i++)
#pragma unroll
            for (int j = 0; j < 4; j++)
                acc[i][j] = __builtin_amdgcn_mfma_f32_16x16x32_bf16(af[i], bf[j], acc[i][j], 0, 0, 0);
        __builtin_amdgcn_s_setprio(0);
        __builtin_amdgcn_sched_barrier(0);
    };

    const int NT = E_DIM / 32;                  // 32 K-tiles
    stage_t(0); stage_t(1);
    for (int t = 0; t < NT - 2; ++t) {
        asm volatile("s_waitcnt vmcnt(6)" ::: "memory");   // tile t's 6 loads landed
        body(t, true);
    }
    asm volatile("s_waitcnt vmcnt(6)" ::: "memory"); body(NT - 2, false);
    asm volatile("s_waitcnt vmcnt(0)" ::: "memory"); body(NT - 1, false);

    // ---- epilogue ----
    const int   mode  = g.mode[seg];
    const float scale = g.scale[seg];
    const float* bias = g.bias[seg];
    void* Cout        = g.C[seg];
#pragma unroll
    for (int j = 0; j < 4; j++) {
        const int col = col0 + wid * 64 + j * 16 + l16;
        const float bv = bias[col];
#pragma unroll
        for (int i = 0; i < 8; i++) {
            const int row = row0 + i * 16 + quad * 4;
            if (mode == 3) {
                // [bh][d][s]: 4 consecutive s per lane -> one packed 8B store
                __attribute__((aligned(8))) __hip_bfloat16 o[4];
#pragma unroll
                for (int r = 0; r < 4; r++) o[r] = __float2bfloat16((acc[i][j][r] + bv) * scale);
                const int b_ = row >> 11, s_ = row & 2047, h_ = col >> 6, d_ = col & 63;
                *reinterpret_cast<uint2*>((__hip_bfloat16*)Cout +
                    (((size_t)(b_ * H_NUM + h_)) << 17) + (d_ << 11) + s_) =
                    *reinterpret_cast<uint2*>(o);
            } else {
#pragma unroll
                for (int r = 0; r < 4; r++) {
                    const float v = (acc[i][j][r] + bv) * scale;
                    const int rr = row + r;
                    if (mode == 0) {
                        ((__hip_bfloat16*)Cout)[(size_t)rr * E_DIM + col] = __float2bfloat16(v);
                    } else if (mode == 1) {
                        ((float*)Cout)[(size_t)rr * E_DIM + col] = v;
                    } else {
                        const int b_ = rr >> 11, s_ = rr & 2047, h_ = col >> 6, d_ = col & 63;
                        ((__hip_bfloat16*)Cout)[(((size_t)(b_ * H_NUM + h_)) << 17) + (s_ << 6) + d_] =
                            __float2bfloat16(v);
                    }
                }
            }
        }
    }
}

// ---------------------------------------------------------------------------
// Flash attention v2, split-KV.  512 threads = 8 waves: waves 0-3 own 64
// q-rows each with keys [0,1024); waves 4-7 the SAME rows, keys [1024,2048).
// 16 waves/CU (4/SIMD, was 2/SIMD): doubles the number of per-chunk serial
// chains (QK MFMA -> exp2/pack -> P LDS -> PV) in flight per SIMD while
// keeping full work per chain (R2's failure mode was halving chain work).
// The no-max exp2 softmax makes the split EXACT: o_acc and lsum are plain
// sums, merged by LDS add (2 phases of 32KB reusing the dead P buffer).
// Register double-buffer K/V prefetch + bh->XCD pinning kept from R3.
// ---------------------------------------------------------------------------
__global__ __launch_bounds__(512, 4) void attn(const __hip_bfloat16* __restrict__ Qt,
                                               const __hip_bfloat16* __restrict__ Kt,
                                               const __hip_bfloat16* __restrict__ Vt,
                                               __hip_bfloat16* __restrict__ Op)
{
    __shared__ __attribute__((aligned(16))) __hip_bfloat16 Pls[8][64][40];   // 40 KB

    const int x = blockIdx.x;                   // 512 blocks
    const int xcd = x & 7, idx = x >> 3;        // dispatch: block x -> XCD x%8
    const int bh     = xcd * 8 + (idx & 7);     // all 8 q-chunks of bh on one XCD
    const int qchunk = idx >> 3;                // 0..7, 256 q-rows each
    const int wave = threadIdx.x >> 6, lane = threadIdx.x & 63;
    const int quad = lane >> 4, l16 = lane & 15;
    const int rw = wave & 3, kshalf = wave >> 2;
    const int qrow0 = qchunk * 256 + rw * 64;
    const int kvbase = kshalf << 10;            // 0 or 1024

    const __hip_bfloat16* qb = Qt + ((size_t)bh << 17);
    const __hip_bfloat16* kb = Kt + ((size_t)bh << 17);
    const __hip_bfloat16* vb = Vt + ((size_t)bh << 17);
    __hip_bfloat16* pw = &Pls[wave][0][0];

    // Q fragments: 4 q-tiles x 2 d-halves (B-operand layout), held all kernel.
    bf16x8 qf[4][2];
#pragma unroll
    for (int qt = 0; qt < 4; qt++) {
        qf[qt][0] = load8(qb + ((qrow0 + qt * 16 + l16) << 6) + quad * 8);
        qf[qt][1] = load8(qb + ((qrow0 + qt * 16 + l16) << 6) + 32 + quad * 8);
    }

    const f32x4 zero = {0.f, 0.f, 0.f, 0.f};
    f32x4 o_acc[4][4];
#pragma unroll
    for (int qt = 0; qt < 4; qt++)
#pragma unroll
        for (int dj = 0; dj < 4; dj++) o_acc[qt][dj] = zero;
    float lsum[4] = {0.f, 0.f, 0.f, 0.f};

    // K/V register sets for one 32-key chunk: K 2 tiles x 2 d-halves, V 4 frags.
    bf16x8 kaA[2], kcA[2], vfA[4], kaB[2], kcB[2], vfB[4];

    auto prefetch = [&](bf16x8 (&ka)[2], bf16x8 (&kc)[2], bf16x8 (&vf)[4], int kv) {
#pragma unroll
        for (int t = 0; t < 2; t++) {
            ka[t] = load8(kb + ((kv + t * 16 + l16) << 6) + quad * 8);
            kc[t] = load8(kb + ((kv + t * 16 + l16) << 6) + 32 + quad * 8);
        }
#pragma unroll
        for (int dj = 0; dj < 4; dj++)
            vf[dj] = load8(vb + ((size_t)(dj * 16 + l16) << 11) + kv + quad * 8);
    };

    auto compute = [&](const bf16x8 (&ka)[2], const bf16x8 (&kc)[2], const bf16x8 (&vf)[4]) {
        // ---- S^T = K·Q^T for 2 key-tiles; p = exp2(s); pack to P ----
#pragma unroll
        for (int t = 0; t < 2; t++) {
#pragma unroll
            for (int qt = 0; qt < 4; qt++) {
                f32x4 st = __builtin_amdgcn_mfma_f32_16x16x32_bf16(ka[t], qf[qt][0], zero, 0, 0, 0);
                st       = __builtin_amdgcn_mfma_f32_16x16x32_bf16(kc[t], qf[qt][1], st, 0, 0, 0);
                const float p0 = EXP2F(st[0]), p1 = EXP2F(st[1]);
                const float p2 = EXP2F(st[2]), p3 = EXP2F(st[3]);
                lsum[qt] += (p0 + p1) + (p2 + p3);
                const unsigned u0 = (unsigned)__bfloat16_as_ushort(__float2bfloat16(p0));
                const unsigned u1 = (unsigned)__bfloat16_as_ushort(__float2bfloat16(p1));
                const unsigned u2 = (unsigned)__bfloat16_as_ushort(__float2bfloat16(p2));
                const unsigned u3 = (unsigned)__bfloat16_as_ushort(__float2bfloat16(p3));
                uint2 w;
                w.x = (u1 << 16) | u0;
                w.y = (u3 << 16) | u2;
                *reinterpret_cast<uint2*>(&pw[(qt * 16 + l16) * 40 + t * 16 + quad * 4]) = w;
            }
        }
        // ---- O += P·V ----
        __builtin_amdgcn_s_setprio(1);
#pragma unroll
        for (int qt = 0; qt < 4; qt++) {
            const bf16x8 pa = load8(&pw[(qt * 16 + l16) * 40 + quad * 8]);
#pragma unroll
            for (int dj = 0; dj < 4; dj++)
                o_acc[qt][dj] = __builtin_amdgcn_mfma_f32_16x16x32_bf16(pa, vf[dj], o_acc[qt][dj], 0, 0, 0);
        }
        __builtin_amdgcn_s_setprio(0);
    };

    prefetch(kaA, kcA, vfA, kvbase);
    for (int kv0 = kvbase; kv0 < kvbase + 1024; kv0 += 64) {
        prefetch(kaB, kcB, vfB, (kv0 + 32) & (S_LEN - 1));
        __builtin_amdgcn_sched_barrier(0);
        compute(kaA, kcA, vfA);
        prefetch(kaA, kcA, vfA, (kv0 + 64) & (S_LEN - 1));   // wraps; read unused
        __builtin_amdgcn_sched_barrier(0);
        compute(kaB, kcB, vfB);
    }

    // ---- split-KV merge: waves 4-7 hand partials to waves 0-3 via LDS ----
    // Layout (floats, reusing Pls):
    //   acc slot (rw, q2, dj): [((rw*2+q2)*4+dj)*256 + lane*4], f32x4
    //   lsum slot: [8192 + (rw*2+q2)*64 + lane]
    float* mb = reinterpret_cast<float*>(&Pls[0][0][0]);
    __syncthreads();                            // all P reads done before reuse
#pragma unroll
    for (int ph = 0; ph < 2; ph++) {            // phase 0: qt 0-1, phase 1: qt 2-3
        if (kshalf == 1) {
#pragma unroll
            for (int q2 = 0; q2 < 2; q2++) {
                const int qt = ph * 2 + q2;
#pragma unroll
                for (int dj = 0; dj < 4; dj++)
                    *reinterpret_cast<f32x4*>(&mb[(((rw * 2 + q2) * 4 + dj) << 8) + (lane << 2)]) = o_acc[qt][dj];
                mb[8192 + (rw * 2 + q2) * 64 + lane] = lsum[qt];
            }
        }
        __syncthreads();
        if (kshalf == 0) {
#pragma unroll
            for (int q2 = 0; q2 < 2; q2++) {
                const int qt = ph * 2 + q2;
#pragma unroll
                for (int dj = 0; dj < 4; dj++) {
                    const f32x4 v = *reinterpret_cast<const f32x4*>(&mb[(((rw * 2 + q2) * 4 + dj) << 8) + (lane << 2)]);
                    o_acc[qt][dj] += v;
                }
                lsum[qt] += mb[8192 + (rw * 2 + q2) * 64 + lane];
            }
        }
        __syncthreads();
    }
    if (kshalf == 1) return;

    // ---- epilogue (waves 0-3): reduce l across quads, write C-layout rows ----
    const int b_ = bh >> 4, h_ = bh & 15;
#pragma unroll
    for (int qt = 0; qt < 4; qt++) {
        float l = lsum[qt];
        l += __shfl_xor(l, 16, 64);
        l += __shfl_xor(l, 32, 64);
#pragma unroll
        for (int r = 0; r < 4; r++) {
            const float lr = __shfl(l, quad * 4 + r, 64);   // l of q-row qt*16+quad*4+r
            const float inv = 1.f / lr;
            const size_t ro = ((size_t)b_ * S_LEN + (qrow0 + qt * 16 + quad * 4 + r)) * E_DIM + h_ * D_DIM;
#pragma unroll
            for (int dj = 0; dj < 4; dj++)
                Op[ro + dj * 16 + l16] = __float2bfloat16(o_acc[qt][dj][r] * inv);
        }
    }
}

// ---------------------------------------------------------------------------
extern "C" void kernel_launch(void* const* d_in, const int* in_sizes, int n_in,
                              void* d_out, int out_size, void* d_ws, size_t ws_size,
                              hipStream_t stream)
{
    const float* Qf  = (const float*)d_in[0];
    const float* Kf  = (const float*)d_in[1];
    const float* Vf  = (const float*)d_in[2];
    const float* Wqf = (const float*)d_in[3];
    const float* bqf = (const float*)d_in[4];
    const float* Wkf = (const float*)d_in[5];
    const float* bkf = (const float*)d_in[6];
    const float* Wvf = (const float*)d_in[7];
    const float* bvf = (const float*)d_in[8];
    const float* Wof = (const float*)d_in[9];
    const float* bof = (const float*)d_in[10];

    const size_t n_act = (size_t)M_ROWS * E_DIM;   // 8,388,608
    const size_t n_w   = (size_t)E_DIM * E_DIM;    // 1,048,576

    const dim3 blk(256), gblk(256), ablk(512);
    const int cg_act = (int)(n_act / 8 / 256);
    const int cg_w   = (int)(n_w / 8 / 256);

    const size_t need_fast = (6 * n_act + 4 * n_w) * sizeof(__hip_bfloat16);  // 104 MB

    if (ws_size >= need_fast) {
        // ---- fast path: independent buffers, QKV co-launched (768 wg) ----
        __hip_bfloat16* Xq = (__hip_bfloat16*)d_ws;
        __hip_bfloat16* Xk = Xq + n_act;
        __hip_bfloat16* Xv = Xk + n_act;
        __hip_bfloat16* Wb = Xv + n_act;           // 4 weights back-to-back
        __hip_bfloat16* Qt = Wb + 4 * n_w;
        __hip_bfloat16* Kt = Qt + n_act;
        __hip_bfloat16* Vt = Kt + n_act;

        cvt_f32_bf16<<<cg_act, blk, 0, stream>>>(Qf,  Xq,          (int)(n_act / 8));
        cvt_f32_bf16<<<cg_act, blk, 0, stream>>>(Kf,  Xk,          (int)(n_act / 8));
        cvt_f32_bf16<<<cg_act, blk, 0, stream>>>(Vf,  Xv,          (int)(n_act / 8));
        cvt_f32_bf16<<<cg_w,   blk, 0, stream>>>(Wqf, Wb,          (int)(n_w / 8));
        cvt_f32_bf16<<<cg_w,   blk, 0, stream>>>(Wkf, Wb + n_w,    (int)(n_w / 8));
        cvt_f32_bf16<<<cg_w,   blk, 0, stream>>>(Wvf, Wb + 2*n_w,  (int)(n_w / 8));
        cvt_f32_bf16<<<cg_w,   blk, 0, stream>>>(Wof, Wb + 3*n_w,  (int)(n_w / 8));

        GemmArgs qkv;
        qkv.A[0] = Xq;  qkv.A[1] = Xk;  qkv.A[2] = Xv;
        qkv.W[0] = Wb;  qkv.W[1] = Wb + n_w;  qkv.W[2] = Wb + 2*n_w;
        qkv.bias[0] = bqf;  qkv.bias[1] = bkf;  qkv.bias[2] = bvf;
        qkv.C[0] = Qt;  qkv.C[1] = Kt;  qkv.C[2] = Vt;
        qkv.scale[0] = QK_SCALE;  qkv.scale[1] = 1.0f;  qkv.scale[2] = 1.0f;
        qkv.mode[0] = 2;  qkv.mode[1] = 2;  qkv.mode[2] = 3;
        gemm_bt<<<dim3(768), gblk, 0, stream>>>(qkv);

        attn<<<dim3(512), ablk, 0, stream>>>(Qt, Kt, Vt, Xq);   // Xq free after QKV gemm

        GemmArgs og;
        og.A[0] = Xq;  og.A[1] = Xq;  og.A[2] = Xq;
        og.W[0] = Wb + 3*n_w;  og.W[1] = og.W[0];  og.W[2] = og.W[0];
        og.bias[0] = bof;  og.bias[1] = bof;  og.bias[2] = bof;
        og.C[0] = d_out;  og.C[1] = d_out;  og.C[2] = d_out;
        og.scale[0] = 1.0f;  og.scale[1] = 1.0f;  og.scale[2] = 1.0f;
        og.mode[0] = 1;  og.mode[1] = 1;  og.mode[2] = 1;
        gemm_bt<<<dim3(256), gblk, 0, stream>>>(og);
    } else {
        // ---- fallback: sequential, shared X/Wb buffers (66 MB) ----
        __hip_bfloat16* X  = (__hip_bfloat16*)d_ws;
        __hip_bfloat16* Wb = X + n_act;
        __hip_bfloat16* Qt = Wb + n_w;
        __hip_bfloat16* Kt = Qt + n_act;
        __hip_bfloat16* Vt = Kt + n_act;

        auto one = [&](const float* Af, const float* Wf, const float* bf_,
                       void* C, float sc, int md) {
            cvt_f32_bf16<<<cg_act, blk, 0, stream>>>(Af, X, (int)(n_act / 8));
            cvt_f32_bf16<<<cg_w,   blk, 0, stream>>>(Wf, Wb, (int)(n_w / 8));
            GemmArgs a;
            a.A[0] = X; a.A[1] = X; a.A[2] = X;
            a.W[0] = Wb; a.W[1] = Wb; a.W[2] = Wb;
            a.bias[0] = bf_; a.bias[1] = bf_; a.bias[2] = bf_;
            a.C[0] = C; a.C[1] = C; a.C[2] = C;
            a.scale[0] = sc; a.scale[1] = sc; a.scale[2] = sc;
            a.mode[0] = md; a.mode[1] = md; a.mode[2] = md;
            gemm_bt<<<dim3(256), gblk, 0, stream>>>(a);
        };
        one(Qf, Wqf, bqf, Qt, QK_SCALE, 2);
        one(Kf, Wkf, bkf, Kt, 1.0f, 2);
        one(Vf, Wvf, bvf, Vt, 1.0f, 3);
        attn<<<dim3(512), ablk, 0, stream>>>(Qt, Kt, Vt, X);
        cvt_f32_bf16<<<cg_w, blk, 0, stream>>>(Wof, Wb, (int)(n_w / 8));
        GemmArgs og;
        og.A[0] = X; og.A[1] = X; og.A[2] = X;
        og.W[0] = Wb; og.W[1] = Wb; og.W[2] = Wb;
        og.bias[0] = bof; og.bias[1] = bof; og.bias[2] = bof;
        og.C[0] = d_out; og.C[1] = d_out; og.C[2] = d_out;
        og.scale[0] = 1.0f; og.scale[1] = 1.0f; og.scale[2] = 1.0f;
        og.mode[0] = 1; og.mode[1] = 1; og.mode[2] = 1;
        gemm_bt<<<dim3(256), gblk, 0, stream>>>(og);
    }
}

// Round 5
// 366.956 us; speedup vs baseline: 3.4767x; 3.4767x over previous
//
#include <hip/hip_runtime.h>
#include <hip/hip_bf16.h>

// Problem constants
#define B_SZ   4
#define S_LEN  2048
#define E_DIM  1024
#define H_NUM  16
#define D_DIM  64
#define M_ROWS (B_SZ * S_LEN)            // 8192
#define QK_SCALE 0.1803368801111204f     // (1/sqrt(64)) * log2(e): softmax in exp2 domain

typedef __attribute__((ext_vector_type(8))) __bf16 bf16x8;
typedef __attribute__((ext_vector_type(4))) float  f32x4;

__device__ __forceinline__ bf16x8 load8(const void* p) {
    return __builtin_bit_cast(bf16x8, *reinterpret_cast<const uint4*>(p));
}

#if defined(__has_builtin)
#if __has_builtin(__builtin_amdgcn_exp2f)
#define EXP2F(x) __builtin_amdgcn_exp2f(x)
#endif
#if __has_builtin(__builtin_amdgcn_global_load_lds)
#define HAVE_GLL 1
#endif
#endif
#ifndef EXP2F
#define EXP2F(x) exp2f(x)
#endif

// 16B-per-lane global->LDS stage (wave-uniform LDS base, lane i -> base+16i).
__device__ __forceinline__ void stage16(const __hip_bfloat16* g, __hip_bfloat16* lbase, int lane) {
#ifdef HAVE_GLL
    __builtin_amdgcn_global_load_lds((const __attribute__((address_space(1))) unsigned int*)g,
                                     (__attribute__((address_space(3))) unsigned int*)lbase,
                                     16, 0, 0);
#else
    reinterpret_cast<uint4*>(lbase)[lane] = *reinterpret_cast<const uint4*>(g);
#endif
}

// ---------------------------------------------------------------------------
// Fused f32 -> bf16 convert for ALL 7 tensors in ONE dispatch (launch-overhead
// elimination: 7 launches -> 1).  Segments: 0-2 activations (2^20 i8-units
// each), 3-6 weights (2^17 each).  Total 3,670,016 units = 14336 x 256.
// ---------------------------------------------------------------------------
#define N8A (1 << 20)
#define N8W (1 << 17)
#define N8TOT (3 * N8A + 4 * N8W)

struct CvtArgs {
    const float* s[7];
    __hip_bfloat16* d[7];
};

__global__ __launch_bounds__(256) void cvt_all(CvtArgs a)
{
    const int i = blockIdx.x * 256 + threadIdx.x;
    if (i >= N8TOT) return;
    int seg, off;
    if (i < 3 * N8A) { seg = i >> 20;              off = i & (N8A - 1); }
    else             { const int j = i - 3 * N8A;
                       seg = 3 + (j >> 17);        off = j & (N8W - 1); }
    const float* s = a.s[seg];
    __hip_bfloat16* d = a.d[seg];
    const float4 x = reinterpret_cast<const float4*>(s)[off * 2];
    const float4 y = reinterpret_cast<const float4*>(s)[off * 2 + 1];
    __hip_bfloat16 o[8];
    o[0] = __float2bfloat16(x.x); o[1] = __float2bfloat16(x.y);
    o[2] = __float2bfloat16(x.z); o[3] = __float2bfloat16(x.w);
    o[4] = __float2bfloat16(y.x); o[5] = __float2bfloat16(y.y);
    o[6] = __float2bfloat16(y.z); o[7] = __float2bfloat16(y.w);
    reinterpret_cast<uint4*>(d)[off] = *reinterpret_cast<uint4*>(o);
}

// single-tensor cvt kept for the fallback path
__global__ __launch_bounds__(256) void cvt_f32_bf16(const float* __restrict__ s,
                                                    __hip_bfloat16* __restrict__ d,
                                                    int n8)
{
    const int i = blockIdx.x * 256 + threadIdx.x;
    if (i >= n8) return;
    const float4 a = reinterpret_cast<const float4*>(s)[i * 2];
    const float4 b = reinterpret_cast<const float4*>(s)[i * 2 + 1];
    __hip_bfloat16 o[8];
    o[0] = __float2bfloat16(a.x); o[1] = __float2bfloat16(a.y);
    o[2] = __float2bfloat16(a.z); o[3] = __float2bfloat16(a.w);
    o[4] = __float2bfloat16(b.x); o[5] = __float2bfloat16(b.y);
    o[6] = __float2bfloat16(b.z); o[7] = __float2bfloat16(b.w);
    reinterpret_cast<uint4*>(d)[i] = *reinterpret_cast<uint4*>(o);
}

// ---------------------------------------------------------------------------
// Pipelined GEMM (R3-measured version, verbatim): C = A @ W^T + bias.
// BM=128, BN=256, BK=32, K=1024.  512 threads = 8 waves, 64x64 out/wave.
// 3-buffer LDS ring (72KB); prefetch distance 2; vmcnt(3) steady (never 0).
// LDS swizzle: linear gll dest + inverse-permuted global source + XOR ds_read.
// ---------------------------------------------------------------------------
struct GemmArgs {
    const __hip_bfloat16* A[3];
    const __hip_bfloat16* W[3];
    const float* bias[3];
    void* C[3];
    float scale[3];
    int mode[3];
};

__global__ __launch_bounds__(512, 4) void gemm_bt(GemmArgs g)
{
    __shared__ __attribute__((aligned(16))) char lds_raw[3 * 24576];   // 72 KB ring

    const int tid = threadIdx.x;
    const int wid = tid >> 6, lane = tid & 63;
    const int quad = lane >> 4, l16 = lane & 15;
    const int wm = wid >> 2, wn = wid & 3;

    const int seg = blockIdx.x >> 8;
    int bid = blockIdx.x & 255;
    bid = (bid & 7) * 32 + (bid >> 3);          // XCD-aware swizzle (bijective, 256 wg)
    const int bm = bid >> 2, bn = bid & 3;      // 64 x 4 tiles of 128x256
    const int row0 = bm * 128, col0 = bn * 256;

    const __hip_bfloat16* A = g.A[seg];
    const __hip_bfloat16* W = g.W[seg];

    // --- staging source mapping (linear LDS dest, inverse-swizzled source) ---
    const int s_line = tid >> 3, s_gr = tid & 7;
    const int glin  = s_gr ^ (s_line & 7);
    const int s_row = (s_line << 1) + (glin >> 2);
    const int s_ks  = glin & 3;
    const __hip_bfloat16* gA = A + (size_t)(row0 + s_row) * E_DIM + s_ks * 8;
    const __hip_bfloat16* gB = W + (size_t)(col0 + s_row) * E_DIM + s_ks * 8;
    const int stA = wid << 10;                  // wave-uniform LDS byte offset

    // --- swizzled ds_read byte offsets (per lane), +i*1024 per 16-row frag ---
    const int rg   = (((l16 & 1) << 2) | quad) ^ ((l16 >> 1) & 7);
    const int aoff = (wm * 32 + (l16 >> 1)) * 128 + rg * 16;
    const int boff = (wn * 32 + (l16 >> 1)) * 128 + rg * 16;

    f32x4 acc[4][4];
    const f32x4 zero = {0.f, 0.f, 0.f, 0.f};
#pragma unroll
    for (int i = 0; i < 4; i++)
#pragma unroll
        for (int j = 0; j < 4; j++) acc[i][j] = zero;

    auto stage_t = [&](int t) {
        char* b = lds_raw + (t % 3) * 24576;
        const int ko = t * 32;
        stage16(gA + ko, (__hip_bfloat16*)(b + stA), lane);                          // A 8KB
        stage16(gB + ko, (__hip_bfloat16*)(b + 8192 + stA), lane);                   // B lo
        stage16(gB + (size_t)128 * E_DIM + ko, (__hip_bfloat16*)(b + 16384 + stA), lane); // B hi
    };

    auto body = [&](int t, bool stg) {
        __builtin_amdgcn_s_barrier();
        __builtin_amdgcn_sched_barrier(0);
        if (stg) stage_t(t + 2);
        const char* ab = lds_raw + (t % 3) * 24576;
        bf16x8 af[4], bf[4];
#pragma unroll
        for (int i = 0; i < 4; i++) af[i] = load8(ab + aoff + i * 1024);
#pragma unroll
        for (int j = 0; j < 4; j++) bf[j] = load8(ab + 8192 + boff + j * 1024);
        __builtin_amdgcn_s_setprio(1);
#pragma unroll
        for (int i = 0; i < 4; i++)
#pragma unroll
            for (int j = 0; j < 4; j++)
                acc[i][j] = __builtin_amdgcn_mfma_f32_16x16x32_bf16(af[i], bf[j], acc[i][j], 0, 0, 0);
        __builtin_amdgcn_s_setprio(0);
        __builtin_amdgcn_sched_barrier(0);
    };

    const int NT = E_DIM / 32;                  // 32 K-tiles
    stage_t(0); stage_t(1);
    for (int t = 0; t < NT - 2; ++t) {
        asm volatile("s_waitcnt vmcnt(3)" ::: "memory");   // tile t's 3 loads landed
        body(t, true);
    }
    asm volatile("s_waitcnt vmcnt(3)" ::: "memory"); body(NT - 2, false);
    asm volatile("s_waitcnt vmcnt(0)" ::: "memory"); body(NT - 1, false);

    // ---- epilogue ----
    const int   mode  = g.mode[seg];
    const float scale = g.scale[seg];
    const float* bias = g.bias[seg];
    void* Cout        = g.C[seg];
#pragma unroll
    for (int j = 0; j < 4; j++) {
        const int col = col0 + wn * 64 + j * 16 + l16;
        const float bv = bias[col];
#pragma unroll
        for (int i = 0; i < 4; i++) {
            const int row = row0 + wm * 64 + i * 16 + quad * 4;
            if (mode == 3) {
                __attribute__((aligned(8))) __hip_bfloat16 o[4];
#pragma unroll
                for (int r = 0; r < 4; r++) o[r] = __float2bfloat16((acc[i][j][r] + bv) * scale);
                const int b_ = row >> 11, s_ = row & 2047, h_ = col >> 6, d_ = col & 63;
                *reinterpret_cast<uint2*>((__hip_bfloat16*)Cout +
                    (((size_t)(b_ * H_NUM + h_)) << 17) + (d_ << 11) + s_) =
                    *reinterpret_cast<uint2*>(o);
            } else {
#pragma unroll
                for (int r = 0; r < 4; r++) {
                    const float v = (acc[i][j][r] + bv) * scale;
                    const int rr = row + r;
                    if (mode == 0) {
                        ((__hip_bfloat16*)Cout)[(size_t)rr * E_DIM + col] = __float2bfloat16(v);
                    } else if (mode == 1) {
                        ((float*)Cout)[(size_t)rr * E_DIM + col] = v;
                    } else {
                        const int b_ = rr >> 11, s_ = rr & 2047, h_ = col >> 6, d_ = col & 63;
                        ((__hip_bfloat16*)Cout)[(((size_t)(b_ * H_NUM + h_)) << 17) + (s_ << 6) + d_] =
                            __float2bfloat16(v);
                    }
                }
            }
        }
    }
}

// ---------------------------------------------------------------------------
// Flash attention v2 (R3-measured version, verbatim): barrier-free, 64 q-rows
// per wave (4 q-tiles), S^T trick, no-max exp2-domain softmax.
// 512 blocks = 64 bh x 8 q-chunks; register double-buffer K/V prefetch;
// bh->XCD pinning (K+V working set 4MB = one L2); setprio around PV.
// ---------------------------------------------------------------------------
__global__ __launch_bounds__(256) void attn(const __hip_bfloat16* __restrict__ Qt,
                                            const __hip_bfloat16* __restrict__ Kt,
                                            const __hip_bfloat16* __restrict__ Vt,
                                            __hip_bfloat16* __restrict__ Op)
{
    __shared__ __hip_bfloat16 Pls[4][64][40];   // per-wave [qrow][key32 + pad], 20 KB

    const int x = blockIdx.x;                   // 512 blocks
    const int xcd = x & 7, idx = x >> 3;        // dispatch: block x -> XCD x%8
    const int bh     = xcd * 8 + (idx & 7);     // all 8 q-chunks of bh on one XCD
    const int qchunk = idx >> 3;                // 0..7, 256 q-rows each
    const int wave = threadIdx.x >> 6, lane = threadIdx.x & 63;
    const int quad = lane >> 4, l16 = lane & 15;
    const int qrow0 = qchunk * 256 + wave * 64;

    const __hip_bfloat16* qb = Qt + ((size_t)bh << 17);
    const __hip_bfloat16* kb = Kt + ((size_t)bh << 17);
    const __hip_bfloat16* vb = Vt + ((size_t)bh << 17);
    __hip_bfloat16* pw = &Pls[wave][0][0];

    // Q fragments: 4 q-tiles x 2 d-halves (B-operand layout), held all kernel.
    bf16x8 qf[4][2];
#pragma unroll
    for (int qt = 0; qt < 4; qt++) {
        qf[qt][0] = load8(qb + ((qrow0 + qt * 16 + l16) << 6) + quad * 8);
        qf[qt][1] = load8(qb + ((qrow0 + qt * 16 + l16) << 6) + 32 + quad * 8);
    }

    const f32x4 zero = {0.f, 0.f, 0.f, 0.f};
    f32x4 o_acc[4][4];
#pragma unroll
    for (int qt = 0; qt < 4; qt++)
#pragma unroll
        for (int dj = 0; dj < 4; dj++) o_acc[qt][dj] = zero;
    float lsum[4] = {0.f, 0.f, 0.f, 0.f};

    // K/V register sets for one 32-key chunk: K 2 tiles x 2 d-halves, V 4 frags.
    bf16x8 kaA[2], kcA[2], vfA[4], kaB[2], kcB[2], vfB[4];

    auto prefetch = [&](bf16x8 (&ka)[2], bf16x8 (&kc)[2], bf16x8 (&vf)[4], int kv) {
#pragma unroll
        for (int t = 0; t < 2; t++) {
            ka[t] = load8(kb + ((kv + t * 16 + l16) << 6) + quad * 8);
            kc[t] = load8(kb + ((kv + t * 16 + l16) << 6) + 32 + quad * 8);
        }
#pragma unroll
        for (int dj = 0; dj < 4; dj++)
            vf[dj] = load8(vb + ((size_t)(dj * 16 + l16) << 11) + kv + quad * 8);
    };

    auto compute = [&](const bf16x8 (&ka)[2], const bf16x8 (&kc)[2], const bf16x8 (&vf)[4]) {
        // ---- S^T = K·Q^T for 2 key-tiles; p = exp2(s); pack to P ----
#pragma unroll
        for (int t = 0; t < 2; t++) {
#pragma unroll
            for (int qt = 0; qt < 4; qt++) {
                f32x4 st = __builtin_amdgcn_mfma_f32_16x16x32_bf16(ka[t], qf[qt][0], zero, 0, 0, 0);
                st       = __builtin_amdgcn_mfma_f32_16x16x32_bf16(kc[t], qf[qt][1], st, 0, 0, 0);
                const float p0 = EXP2F(st[0]), p1 = EXP2F(st[1]);
                const float p2 = EXP2F(st[2]), p3 = EXP2F(st[3]);
                lsum[qt] += (p0 + p1) + (p2 + p3);
                const unsigned u0 = (unsigned)__bfloat16_as_ushort(__float2bfloat16(p0));
                const unsigned u1 = (unsigned)__bfloat16_as_ushort(__float2bfloat16(p1));
                const unsigned u2 = (unsigned)__bfloat16_as_ushort(__float2bfloat16(p2));
                const unsigned u3 = (unsigned)__bfloat16_as_ushort(__float2bfloat16(p3));
                uint2 w;
                w.x = (u1 << 16) | u0;
                w.y = (u3 << 16) | u2;
                *reinterpret_cast<uint2*>(&pw[(qt * 16 + l16) * 40 + t * 16 + quad * 4]) = w;
            }
        }
        // ---- O += P·V ----
        __builtin_amdgcn_s_setprio(1);
#pragma unroll
        for (int qt = 0; qt < 4; qt++) {
            const bf16x8 pa = load8(&pw[(qt * 16 + l16) * 40 + quad * 8]);
#pragma unroll
            for (int dj = 0; dj < 4; dj++)
                o_acc[qt][dj] = __builtin_amdgcn_mfma_f32_16x16x32_bf16(pa, vf[dj], o_acc[qt][dj], 0, 0, 0);
        }
        __builtin_amdgcn_s_setprio(0);
    };

    prefetch(kaA, kcA, vfA, 0);
    for (int kv0 = 0; kv0 < S_LEN; kv0 += 64) {
        prefetch(kaB, kcB, vfB, (kv0 + 32) & (S_LEN - 1));
        __builtin_amdgcn_sched_barrier(0);
        compute(kaA, kcA, vfA);
        prefetch(kaA, kcA, vfA, (kv0 + 64) & (S_LEN - 1));   // wraps; read unused
        __builtin_amdgcn_sched_barrier(0);
        compute(kaB, kcB, vfB);
    }

    // ---- epilogue: reduce l across quads, redistribute to C-layout rows ----
    const int b_ = bh >> 4, h_ = bh & 15;
#pragma unroll
    for (int qt = 0; qt < 4; qt++) {
        float l = lsum[qt];
        l += __shfl_xor(l, 16, 64);
        l += __shfl_xor(l, 32, 64);
#pragma unroll
        for (int r = 0; r < 4; r++) {
            const float lr = __shfl(l, quad * 4 + r, 64);   // l of q-row qt*16+quad*4+r
            const float inv = 1.f / lr;
            const size_t ro = ((size_t)b_ * S_LEN + (qrow0 + qt * 16 + quad * 4 + r)) * E_DIM + h_ * D_DIM;
#pragma unroll
            for (int dj = 0; dj < 4; dj++)
                Op[ro + dj * 16 + l16] = __float2bfloat16(o_acc[qt][dj][r] * inv);
        }
    }
}

// ---------------------------------------------------------------------------
extern "C" void kernel_launch(void* const* d_in, const int* in_sizes, int n_in,
                              void* d_out, int out_size, void* d_ws, size_t ws_size,
                              hipStream_t stream)
{
    const float* Qf  = (const float*)d_in[0];
    const float* Kf  = (const float*)d_in[1];
    const float* Vf  = (const float*)d_in[2];
    const float* Wqf = (const float*)d_in[3];
    const float* bqf = (const float*)d_in[4];
    const float* Wkf = (const float*)d_in[5];
    const float* bkf = (const float*)d_in[6];
    const float* Wvf = (const float*)d_in[7];
    const float* bvf = (const float*)d_in[8];
    const float* Wof = (const float*)d_in[9];
    const float* bof = (const float*)d_in[10];

    const size_t n_act = (size_t)M_ROWS * E_DIM;   // 8,388,608
    const size_t n_w   = (size_t)E_DIM * E_DIM;    // 1,048,576

    const dim3 blk(256), gblk(512), ablk(256);
    const int cg_act = (int)(n_act / 8 / 256);
    const int cg_w   = (int)(n_w / 8 / 256);

    const size_t need_fast = (6 * n_act + 4 * n_w) * sizeof(__hip_bfloat16);  // 104 MB

    if (ws_size >= need_fast) {
        // ---- fast path: 4 dispatches total (was 10) ----
        __hip_bfloat16* Xq = (__hip_bfloat16*)d_ws;
        __hip_bfloat16* Xk = Xq + n_act;
        __hip_bfloat16* Xv = Xk + n_act;
        __hip_bfloat16* Wb = Xv + n_act;           // 4 weights back-to-back
        __hip_bfloat16* Qt = Wb + 4 * n_w;
        __hip_bfloat16* Kt = Qt + n_act;
        __hip_bfloat16* Vt = Kt + n_act;

        // 1) all conversions in one launch
        CvtArgs ca;
        ca.s[0] = Qf;  ca.s[1] = Kf;  ca.s[2] = Vf;
        ca.s[3] = Wqf; ca.s[4] = Wkf; ca.s[5] = Wvf; ca.s[6] = Wof;
        ca.d[0] = Xq;  ca.d[1] = Xk;  ca.d[2] = Xv;
        ca.d[3] = Wb;  ca.d[4] = Wb + n_w; ca.d[5] = Wb + 2 * n_w; ca.d[6] = Wb + 3 * n_w;
        cvt_all<<<dim3(N8TOT / 256), blk, 0, stream>>>(ca);

        // 2) QKV projections co-launched
        GemmArgs qkv;
        qkv.A[0] = Xq;  qkv.A[1] = Xk;  qkv.A[2] = Xv;
        qkv.W[0] = Wb;  qkv.W[1] = Wb + n_w;  qkv.W[2] = Wb + 2*n_w;
        qkv.bias[0] = bqf;  qkv.bias[1] = bkf;  qkv.bias[2] = bvf;
        qkv.C[0] = Qt;  qkv.C[1] = Kt;  qkv.C[2] = Vt;
        qkv.scale[0] = QK_SCALE;  qkv.scale[1] = 1.0f;  qkv.scale[2] = 1.0f;
        qkv.mode[0] = 2;  qkv.mode[1] = 2;  qkv.mode[2] = 3;
        gemm_bt<<<dim3(768), gblk, 0, stream>>>(qkv);

        // 3) attention -> Xq (free after QKV gemm)
        attn<<<dim3(512), ablk, 0, stream>>>(Qt, Kt, Vt, Xq);

        // 4) output projection -> f32 d_out
        GemmArgs og;
        og.A[0] = Xq;  og.A[1] = Xq;  og.A[2] = Xq;
        og.W[0] = Wb + 3*n_w;  og.W[1] = og.W[0];  og.W[2] = og.W[0];
        og.bias[0] = bof;  og.bias[1] = bof;  og.bias[2] = bof;
        og.C[0] = d_out;  og.C[1] = d_out;  og.C[2] = d_out;
        og.scale[0] = 1.0f;  og.scale[1] = 1.0f;  og.scale[2] = 1.0f;
        og.mode[0] = 1;  og.mode[1] = 1;  og.mode[2] = 1;
        gemm_bt<<<dim3(256), gblk, 0, stream>>>(og);
    } else {
        // ---- fallback: sequential, shared X/Wb buffers (66 MB) ----
        __hip_bfloat16* X  = (__hip_bfloat16*)d_ws;
        __hip_bfloat16* Wb = X + n_act;
        __hip_bfloat16* Qt = Wb + n_w;
        __hip_bfloat16* Kt = Qt + n_act;
        __hip_bfloat16* Vt = Kt + n_act;

        auto one = [&](const float* Af, const float* Wf, const float* bf_,
                       void* C, float sc, int md) {
            cvt_f32_bf16<<<cg_act, blk, 0, stream>>>(Af, X, (int)(n_act / 8));
            cvt_f32_bf16<<<cg_w,   blk, 0, stream>>>(Wf, Wb, (int)(n_w / 8));
            GemmArgs a;
            a.A[0] = X; a.A[1] = X; a.A[2] = X;
            a.W[0] = Wb; a.W[1] = Wb; a.W[2] = Wb;
            a.bias[0] = bf_; a.bias[1] = bf_; a.bias[2] = bf_;
            a.C[0] = C; a.C[1] = C; a.C[2] = C;
            a.scale[0] = sc; a.scale[1] = sc; a.scale[2] = sc;
            a.mode[0] = md; a.mode[1] = md; a.mode[2] = md;
            gemm_bt<<<dim3(256), gblk, 0, stream>>>(a);
        };
        one(Qf, Wqf, bqf, Qt, QK_SCALE, 2);
        one(Kf, Wkf, bkf, Kt, 1.0f, 2);
        one(Vf, Wvf, bvf, Vt, 1.0f, 3);
        attn<<<dim3(512), ablk, 0, stream>>>(Qt, Kt, Vt, X);
        cvt_f32_bf16<<<cg_w, blk, 0, stream>>>(Wof, Wb, (int)(n_w / 8));
        GemmArgs og;
        og.A[0] = X; og.A[1] = X; og.A[2] = X;
        og.W[0] = Wb; og.W[1] = Wb; og.W[2] = Wb;
        og.bias[0] = bof; og.bias[1] = bof; og.bias[2] = bof;
        og.C[0] = d_out; og.C[1] = d_out; og.C[2] = d_out;
        og.scale[0] = 1.0f; og.scale[1] = 1.0f; og.scale[2] = 1.0f;
        og.mode[0] = 1; og.mode[1] = 1; og.mode[2] = 1;
        gemm_bt<<<dim3(256), gblk, 0, stream>>>(og);
    }
}